// Round 9
// baseline (369.927 us; speedup 1.0000x reference)
//
#include <hip/hip_runtime.h>
#include <hip/hip_bf16.h>

typedef __bf16 bf16x8 __attribute__((ext_vector_type(8)));
typedef float f32x4 __attribute__((ext_vector_type(4)));
typedef int i32x4 __attribute__((ext_vector_type(4)));
typedef unsigned short us8 __attribute__((ext_vector_type(8)));
typedef unsigned short us4 __attribute__((ext_vector_type(4)));

__device__ inline float bf2f(unsigned short u) {
  union { unsigned u; float f; } x; x.u = ((unsigned)u) << 16; return x.f;
}
__device__ inline unsigned short f2bf(float f) {
  union { float f; unsigned u; } x; x.f = f;
  unsigned r = x.u + 0x7fffu + ((x.u >> 16) & 1u);  // RNE
  return (unsigned short)(r >> 16);
}

// Bijective chunked-XCD swizzle (m204).
__device__ inline unsigned xcd_chunk(unsigned b, unsigned nwg) {
  const unsigned x = b & 7u, idx = b >> 3;
  const unsigned q = nwg >> 3, r = nwg & 7u;
  const unsigned base = (x < r) ? x * (q + 1u) : r * (q + 1u) + (x - r) * q;
  return base + idx;
}

__global__ __launch_bounds__(256) void cast_f32_bf16(
    const float* __restrict__ src, unsigned short* __restrict__ dst, int n4) {
  int i = blockIdx.x * 256 + threadIdx.x;
  if (i >= n4) return;
  float4 f = ((const float4*)src)[i];
  us4 u;
  u[0] = f2bf(f.x); u[1] = f2bf(f.y); u[2] = f2bf(f.z); u[3] = f2bf(f.w);
  *(us4*)&dst[i * 4] = u;
}

#define GLLDS(g, l) __builtin_amdgcn_global_load_lds( \
    (const __attribute__((address_space(1))) void*)(g), \
    (__attribute__((address_space(3))) void*)(l), 16, 0, 0)
#define LGKM0  asm volatile("s_waitcnt lgkmcnt(0)" ::: "memory")

// ------- 128x128 m97-structure i8 GEMM for S = exp(QK^T) (BK=64 bytes) -------
// P_q = rn(min(exp(acc*scale)*127/8, 127)) -> i8 C; per-row sums of P_q -> part
// (pidx = (n0/128)*2 + wn, 128 partials/row). Epilogue bounces through a
// per-wave 8KB LDS region (overlaying stage buffers) for coalesced 8B stores.
__global__ __launch_bounds__(256)
void gemm_s_i8(const signed char* __restrict__ A,
               const signed char* __restrict__ B,
               float scale, signed char* __restrict__ C,
               float* __restrict__ part,
               int M, int N, int K, int ldc) {
  __shared__ __align__(16) signed char lds[2][2][8192];
  const int tid = threadIdx.x;
  const int wave = tid >> 6, lane = tid & 63;
  const int wm = wave >> 1, wn = wave & 1;
  const unsigned gx = gridDim.x, nwg = gx * gridDim.y;
  const unsigned w = xcd_chunk(blockIdx.y * gx + blockIdx.x, nwg);
  const long m0 = (long)(w / gx) * 128, n0 = (long)(w % gx) * 128;

  i32x4 acc[4][4];
#pragma unroll
  for (int i = 0; i < 4; ++i)
#pragma unroll
    for (int j = 0; j < 4; ++j) acc[i][j] = (i32x4){0, 0, 0, 0};

  const int srow = tid >> 2;        // 0..63
  const int scol = (tid & 3) * 16;  // byte chunk
#pragma unroll
  for (int j = 0; j < 2; ++j) {
    GLLDS(A + (m0 + j * 64 + srow) * (long)K + scol, &lds[0][0][j * 4096 + wave * 1024]);
    GLLDS(B + (n0 + j * 64 + srow) * (long)K + scol, &lds[0][1][j * 4096 + wave * 1024]);
  }

  const int lr = lane & 15;
  const int lk16 = (lane >> 4) * 16;
  const int KT = K >> 6;
  int cur = 0;
  for (int kt = 0; kt < KT; ++kt) {
    __syncthreads();
    if (kt + 1 < KT) {
      const long k0 = (long)(kt + 1) << 6;
#pragma unroll
      for (int j = 0; j < 2; ++j) {
        GLLDS(A + (m0 + j * 64 + srow) * (long)K + k0 + scol, &lds[cur ^ 1][0][j * 4096 + wave * 1024]);
        GLLDS(B + (n0 + j * 64 + srow) * (long)K + k0 + scol, &lds[cur ^ 1][1][j * 4096 + wave * 1024]);
      }
    }
    i32x4 af[4], bfr[4];
#pragma unroll
    for (int i = 0; i < 4; ++i)
      af[i] = *(const i32x4*)&lds[cur][0][(wm * 64 + i * 16 + lr) * 64 + lk16];
#pragma unroll
    for (int j = 0; j < 4; ++j)
      bfr[j] = *(const i32x4*)&lds[cur][1][(wn * 64 + j * 16 + lr) * 64 + lk16];
#pragma unroll
    for (int i = 0; i < 4; ++i)
#pragma unroll
      for (int j = 0; j < 4; ++j)
        acc[i][j] = __builtin_amdgcn_mfma_i32_16x16x64_i8(af[i], bfr[j], acc[i][j], 0, 0, 0);
    cur ^= 1;
  }

  // ---- epilogue: exp -> quantize; row sums of q; LDS bounce; 8B stores ----
  __syncthreads();  // all waves done reading stage buffers before overlay
  unsigned short* eps = (unsigned short*)&lds[0][0][0] + (size_t)wave * 4096;  // [64][64] u16
  const int cc = lane & 15, cr = (lane >> 4) * 4;
#pragma unroll
  for (int i = 0; i < 4; ++i) {
    float s4[4] = {0.f, 0.f, 0.f, 0.f};
#pragma unroll
    for (int j = 0; j < 4; ++j) {
      const int colp = j * 16 + cc;  // [0,64) within wave quadrant
      const i32x4 v = acc[i][j];
#pragma unroll
      for (int r = 0; r < 4; ++r) {
        const int row = i * 16 + cr + r;  // [0,64)
        const float e = __expf((float)v[r] * scale);
        const float qf = (float)__float2int_rn(fminf(e * 15.875f, 127.0f));
        s4[r] += qf;
        const int phys = ((colp >> 3) ^ (row & 7)) * 8 + (colp & 7);
        eps[row * 64 + phys] = f2bf(qf);  // ints <=127 exact in bf16
      }
    }
#pragma unroll
    for (int r = 0; r < 4; ++r)
#pragma unroll
      for (int o = 1; o < 16; o <<= 1) s4[r] += __shfl_xor(s4[r], o);
    if ((lane & 15) == 0) {
      const long row = m0 + wm * 64 + i * 16 + cr;
      const long pidx = (n0 >> 7) * 2 + wn;
#pragma unroll
      for (int r = 0; r < 4; ++r) part[pidx * (long)M + row + r] = s4[r];
    }
  }
  LGKM0;  // wave-private bounce region ready
#pragma unroll
  for (int p = 0; p < 4; ++p) {
    const int prow = p * 16 + (lane >> 2);  // [0,64)
    const int slot = lane & 3;
#pragma unroll
    for (int gi = 0; gi < 2; ++gi) {
      const int grp = gi * 4 + slot;  // logical 8-col group [0,8)
      us8 vv = *(const us8*)&eps[prow * 64 + ((grp ^ (prow & 7)) * 8)];
      unsigned lo = 0, hi = 0;
#pragma unroll
      for (int j = 0; j < 4; ++j) lo |= ((unsigned)(int)bf2f(vv[j]) & 0xffu) << (8 * j);
#pragma unroll
      for (int j = 0; j < 4; ++j) hi |= ((unsigned)(int)bf2f(vv[4 + j]) & 0xffu) << (8 * j);
      const long grow = m0 + wm * 64 + prow;
      const long gcol = n0 + wn * 64 + grp * 8;
      uint2 pk; pk.x = lo; pk.y = hi;
      *(uint2*)&C[grow * (long)ldc + gcol] = pk;
    }
  }
}

// rowinv[row] = dq / sum_p part[p][row]
__global__ __launch_bounds__(256) void reduce_rowinv(const float* __restrict__ part,
                                                     float* __restrict__ inv, int M, float dq) {
  const int row = blockIdx.x * 256 + threadIdx.x;
  float s = 0.f;
#pragma unroll 8
  for (int p = 0; p < 128; ++p) s += part[(long)p * M + row];
  inv[row] = dq / s;
}

// ------- 128x128 m97-structure i8 GEMM for PV (BK=64 bytes, proven) -------
__global__ __launch_bounds__(256)
void gemm_pv_i8(const signed char* __restrict__ A,
                const signed char* __restrict__ B,
                const float* __restrict__ rowscale,
                unsigned short* __restrict__ C,
                int M, int N, int K, int ldc) {
  __shared__ __align__(16) signed char lds[2][2][8192];
  const int tid = threadIdx.x;
  const int wave = tid >> 6, lane = tid & 63;
  const int wm = wave >> 1, wn = wave & 1;
  const unsigned gx = gridDim.x, nwg = gx * gridDim.y;
  const unsigned w = xcd_chunk(blockIdx.y * gx + blockIdx.x, nwg);
  const long m0 = (long)(w / gx) * 128, n0 = (long)(w % gx) * 128;

  i32x4 acc[4][4];
#pragma unroll
  for (int i = 0; i < 4; ++i)
#pragma unroll
    for (int j = 0; j < 4; ++j) acc[i][j] = (i32x4){0, 0, 0, 0};

  const int srow = tid >> 2;
  const int scol = (tid & 3) * 16;
#pragma unroll
  for (int j = 0; j < 2; ++j) {
    GLLDS(A + (m0 + j * 64 + srow) * (long)K + scol, &lds[0][0][j * 4096 + wave * 1024]);
    GLLDS(B + (n0 + j * 64 + srow) * (long)K + scol, &lds[0][1][j * 4096 + wave * 1024]);
  }

  const int lr = lane & 15;
  const int lk16 = (lane >> 4) * 16;
  const int KT = K >> 6;
  int cur = 0;
  for (int kt = 0; kt < KT; ++kt) {
    __syncthreads();
    if (kt + 1 < KT) {
      const long k0 = (long)(kt + 1) << 6;
#pragma unroll
      for (int j = 0; j < 2; ++j) {
        GLLDS(A + (m0 + j * 64 + srow) * (long)K + k0 + scol, &lds[cur ^ 1][0][j * 4096 + wave * 1024]);
        GLLDS(B + (n0 + j * 64 + srow) * (long)K + k0 + scol, &lds[cur ^ 1][1][j * 4096 + wave * 1024]);
      }
    }
    i32x4 af[4], bfr[4];
#pragma unroll
    for (int i = 0; i < 4; ++i)
      af[i] = *(const i32x4*)&lds[cur][0][(wm * 64 + i * 16 + lr) * 64 + lk16];
#pragma unroll
    for (int j = 0; j < 4; ++j)
      bfr[j] = *(const i32x4*)&lds[cur][1][(wn * 64 + j * 16 + lr) * 64 + lk16];
#pragma unroll
    for (int i = 0; i < 4; ++i)
#pragma unroll
      for (int j = 0; j < 4; ++j)
        acc[i][j] = __builtin_amdgcn_mfma_i32_16x16x64_i8(af[i], bfr[j], acc[i][j], 0, 0, 0);
    cur ^= 1;
  }

  const int cc = lane & 15, cr = (lane >> 4) * 4;
#pragma unroll
  for (int i = 0; i < 4; ++i) {
#pragma unroll
    for (int j = 0; j < 4; ++j) {
      const long grow = m0 + wm * 64 + i * 16 + cr;
      const long gcol = n0 + wn * 64 + j * 16 + cc;
      const i32x4 v = acc[i][j];
#pragma unroll
      for (int r = 0; r < 4; ++r)
        C[(grow + r) * (long)ldc + gcol] = f2bf((float)v[r] * rowscale[grow + r]);
    }
  }
}

// ---------------- 128x128 m97-structure bf16 GEMM (proven) ----------------
// EPI: 2 = relu(v+bias[col]); 5 = i8 quant rn((v+b)*p1) row-major;
//      6 = i8 quant, stored transposed (packed u32 down columns of C^T)
template<int EPI>
__global__ __launch_bounds__(256)
void gemm_bt(const unsigned short* __restrict__ A,
             const unsigned short* __restrict__ B,
             const float* __restrict__ bias, float p1,
             unsigned short* __restrict__ C,
             int M, int N, int K, int ldc) {
  __shared__ unsigned short lds[2][2][4096];
  const int tid = threadIdx.x;
  const int wave = tid >> 6, lane = tid & 63;
  const int wm = wave >> 1, wn = wave & 1;
  const unsigned gx = gridDim.x, nwg = gx * gridDim.y;
  const unsigned w = xcd_chunk(blockIdx.y * gx + blockIdx.x, nwg);
  const long m0 = (long)(w / gx) * 128, n0 = (long)(w % gx) * 128;

  f32x4 acc[4][4];
#pragma unroll
  for (int i = 0; i < 4; ++i)
#pragma unroll
    for (int j = 0; j < 4; ++j) acc[i][j] = (f32x4){0.f, 0.f, 0.f, 0.f};

  const int srow = tid >> 2;
  const int scol = (tid & 3) * 8;
#pragma unroll
  for (int j = 0; j < 2; ++j) {
    const unsigned short* ga = A + (m0 + j * 64 + srow) * K + scol;
    const unsigned short* gb = B + (n0 + j * 64 + srow) * K + scol;
    GLLDS(ga, &lds[0][0][j * 2048 + wave * 512]);
    GLLDS(gb, &lds[0][1][j * 2048 + wave * 512]);
  }

  const int lr = lane & 15;
  const int lk = (lane >> 4) * 8;
  const int KT = K >> 5;
  int cur = 0;
  for (int kt = 0; kt < KT; ++kt) {
    __syncthreads();
    if (kt + 1 < KT) {
      const int k0 = (kt + 1) << 5;
#pragma unroll
      for (int j = 0; j < 2; ++j) {
        const unsigned short* ga = A + (m0 + j * 64 + srow) * K + k0 + scol;
        const unsigned short* gb = B + (n0 + j * 64 + srow) * K + k0 + scol;
        GLLDS(ga, &lds[cur ^ 1][0][j * 2048 + wave * 512]);
        GLLDS(gb, &lds[cur ^ 1][1][j * 2048 + wave * 512]);
      }
    }
    bf16x8 af[4], bfr[4];
#pragma unroll
    for (int i = 0; i < 4; ++i)
      af[i] = *(const bf16x8*)&lds[cur][0][(wm * 64 + i * 16 + lr) * 32 + lk];
#pragma unroll
    for (int j = 0; j < 4; ++j)
      bfr[j] = *(const bf16x8*)&lds[cur][1][(wn * 64 + j * 16 + lr) * 32 + lk];
#pragma unroll
    for (int i = 0; i < 4; ++i)
#pragma unroll
      for (int j = 0; j < 4; ++j)
        acc[i][j] = __builtin_amdgcn_mfma_f32_16x16x32_bf16(af[i], bfr[j], acc[i][j], 0, 0, 0);
    cur ^= 1;
  }

  const int cc = lane & 15, cr = (lane >> 4) * 4;
#pragma unroll
  for (int i = 0; i < 4; ++i) {
#pragma unroll
    for (int j = 0; j < 4; ++j) {
      const long grow = m0 + wm * 64 + i * 16 + cr;
      const long gcol = n0 + wn * 64 + j * 16 + cc;
      f32x4 v = acc[i][j];
      if constexpr (EPI == 2) {
        const float b = bias[gcol];
#pragma unroll
        for (int r = 0; r < 4; ++r)
          C[(grow + r) * (long)ldc + gcol] = f2bf(fmaxf(v[r] + b, 0.f));
      } else if constexpr (EPI == 5) {
        const float b = bias[gcol];
        signed char* Ci = (signed char*)C;
#pragma unroll
        for (int r = 0; r < 4; ++r) {
          int q = __float2int_rn((v[r] + b) * p1);
          q = q > 127 ? 127 : (q < -127 ? -127 : q);
          Ci[(grow + r) * (long)ldc + gcol] = (signed char)q;
        }
      } else {  // EPI == 6: i8 quant transposed; ldc = byte stride of C^T rows
        const float b = bias[gcol];
        signed char* Ci = (signed char*)C;
        unsigned pk = 0;
#pragma unroll
        for (int r = 0; r < 4; ++r) {
          int q = __float2int_rn((v[r] + b) * p1);
          q = q > 127 ? 127 : (q < -127 ? -127 : q);
          pk |= ((unsigned)q & 0xffu) << (8 * r);
        }
        *(unsigned*)&Ci[gcol * (long)ldc + grow] = pk;
      }
    }
  }
}

__global__ __launch_bounds__(256) void final_dot(const unsigned short* __restrict__ H,
                                                 const float* __restrict__ w,
                                                 float* __restrict__ out) {
  const int lane = threadIdx.x & 63, wave = threadIdx.x >> 6;
  const int row = blockIdx.x * 4 + wave;
  const unsigned short* h = H + (size_t)row * 1024;
  float s = 0.f;
#pragma unroll
  for (int k = 0; k < 2; ++k) {
    const int base = (lane + k * 64) * 8;
    us8 u = *(const us8*)&h[base];
#pragma unroll
    for (int r = 0; r < 8; ++r) s += bf2f(u[r]) * w[base + r];
  }
#pragma unroll
  for (int o = 32; o; o >>= 1) s += __shfl_xor(s, o);
  if (lane == 0) out[row] = s;
}

extern "C" void kernel_launch(void* const* d_in, const int* in_sizes, int n_in,
                              void* d_out, int out_size, void* d_ws, size_t ws_size,
                              hipStream_t stream) {
  const float* x  = (const float*)d_in[0];
  const float* Wq = (const float*)d_in[1];
  const float* bq = (const float*)d_in[2];
  const float* Wk = (const float*)d_in[3];
  const float* bk = (const float*)d_in[4];
  const float* Wv = (const float*)d_in[5];
  const float* bv = (const float*)d_in[6];
  const float* W1 = (const float*)d_in[7];
  const float* b1 = (const float*)d_in[8];
  const float* W2 = (const float*)d_in[9];
  const float* b2 = (const float*)d_in[10];
  const float* W3 = (const float*)d_in[11];
  const float* b3 = (const float*)d_in[12];
  const float* fw = (const float*)d_in[13];
  float* out = (float*)d_out;

  const int N = 8192, D = 1024;
  char* ws = (char*)d_ws;
  signed char* Si8 = (signed char*)ws;                             // [N][N] i8, 64 MB
  unsigned short* xb  = (unsigned short*)(ws + (size_t)N * N * 2);
  unsigned short* Qb  = xb + (size_t)N * D;
  unsigned short* Kb  = Qb + (size_t)N * D;
  unsigned short* Vt  = Kb + (size_t)N * D;                        // region: V^T i8 [D][N]
  unsigned short* Wqb = Vt + (size_t)N * D;
  unsigned short* Wkb = Wqb + (size_t)D * D;
  unsigned short* Wvb = Wkb + (size_t)D * D;
  unsigned short* W1b = Wvb + (size_t)D * D;
  unsigned short* W2b = W1b + (size_t)D * D;
  unsigned short* W3b = W2b + (size_t)D * D;
  float* part   = (float*)(W3b + (size_t)D * D);                   // [128][N] 4 MB
  float* rowinv = part + (size_t)128 * N;                          // [N]
  signed char* Qi8 = (signed char*)Qb;
  signed char* Ki8 = (signed char*)Kb;
  signed char* Vti8 = (signed char*)Vt;
  unsigned short* att = xb;
  unsigned short* H1  = Qb;
  unsigned short* H2  = Kb;
  unsigned short* H3  = Vt;

  cast_f32_bf16<<<(N * D / 4 + 255) / 256, 256, 0, stream>>>(x, xb, N * D / 4);
  cast_f32_bf16<<<(D * D / 4 + 255) / 256, 256, 0, stream>>>(Wq, Wqb, D * D / 4);
  cast_f32_bf16<<<(D * D / 4 + 255) / 256, 256, 0, stream>>>(Wk, Wkb, D * D / 4);
  cast_f32_bf16<<<(D * D / 4 + 255) / 256, 256, 0, stream>>>(Wv, Wvb, D * D / 4);
  cast_f32_bf16<<<(D * D / 4 + 255) / 256, 256, 0, stream>>>(W1, W1b, D * D / 4);
  cast_f32_bf16<<<(D * D / 4 + 255) / 256, 256, 0, stream>>>(W2, W2b, D * D / 4);
  cast_f32_bf16<<<(D * D / 4 + 255) / 256, 256, 0, stream>>>(W3, W3b, D * D / 4);

  const dim3 blk(256);
  // ---- Q,K -> i8 row-major (scale 127/4); V -> i8 transposed [D][N] ----
  gemm_bt<5><<<dim3(D / 128, N / 128), blk, 0, stream>>>(xb, Wqb, bq, 31.75f, Qb, N, D, D, D);
  gemm_bt<5><<<dim3(D / 128, N / 128), blk, 0, stream>>>(xb, Wkb, bk, 31.75f, Kb, N, D, D, D);
  gemm_bt<6><<<dim3(D / 128, N / 128), blk, 0, stream>>>(xb, Wvb, bv, 31.75f, Vt, N, D, D, N);
  // ---- P_q = quant_exp((Qi8.Ki8^T)*dq^2/32), fused row sums of q ----
  const float dq = 4.0f / 127.0f;
  gemm_s_i8<<<dim3(N / 128, N / 128), blk, 0, stream>>>(
      Qi8, Ki8, dq * dq / 32.0f, Si8, part, N, N, D, N);
  // rowinv = dqV / sum(q)   (P dequant scale cancels; V scale folded here)
  reduce_rowinv<<<N / 256, 256, 0, stream>>>(part, rowinv, N, dq);
  // ---- attended = (P_q . Vt_i8^T) * rowinv  (i8 MFMA, K=8192) ----
  gemm_pv_i8<<<dim3(D / 128, N / 128), blk, 0, stream>>>(Si8, Vti8, rowinv, att, N, D, N, D);
  // ---- MLP (bf16) ----
  gemm_bt<2><<<dim3(D / 128, N / 128), blk, 0, stream>>>(att, W1b, b1, 0.f, H1, N, D, D, D);
  gemm_bt<2><<<dim3(D / 128, N / 128), blk, 0, stream>>>(H1, W2b, b2, 0.f, H2, N, D, D, D);
  gemm_bt<2><<<dim3(D / 128, N / 128), blk, 0, stream>>>(H2, W3b, b3, 0.f, H3, N, D, D, D);
  final_dot<<<N / 4, 256, 0, stream>>>(H3, fw, out);
}